// Round 2
// baseline (1212.265 us; speedup 1.0000x reference)
//
#include <hip/hip_runtime.h>
#include <hip/hip_bf16.h>
#include <cstdint>
#include <cstddef>

#define DI __device__ __forceinline__

typedef __bf16 bf16_t;
typedef bf16_t bf16x8 __attribute__((ext_vector_type(8)));
typedef float f32x4 __attribute__((ext_vector_type(4)));
typedef unsigned int u32;
typedef unsigned long long u64;

// problem constants
constexpr int S_ = 128, B_ = 32, I_ = 512, H_ = 512, O_ = 512, E_ = 8;
constexpr int Ntok = S_ * B_;        // 4096
constexpr int G4 = 4 * H_;           // 2048
constexpr int ROWS = 64;             // 2(k) x 32(batch) chains per expert
constexpr int SLOT = E_ * ROWS * H_; // elems per h_all step slot (262144)

// workspace layout (bytes)
constexpr size_t OFF_CNT  = 0;                               // int[8]
constexpr size_t OFF_BAR  = 64;                              // u32 @ +e*64
constexpr size_t OFF_XCDM = 640;                             // u32 @ +e*64
constexpr size_t OFF_XCDG = 1216;                            // u32
constexpr size_t OFF_MASK = 2048;                            // u64 [e*128+t]
constexpr size_t OFF_HALL = 16384;                           // bf16, 129 slots
constexpr size_t SLOT_B   = (size_t)SLOT * 2;
constexpr size_t ZERO_BYTES = OFF_HALL + SLOT_B;             // zero slot 0 too
constexpr size_t OFF_TIDX = OFF_HALL + 129ull * SLOT_B;      // int [Ntok*2]
constexpr size_t OFF_RW   = OFF_TIDX + (size_t)Ntok * 2 * 4; // float [Ntok*2]
constexpr size_t OFF_LIST = OFF_RW + (size_t)Ntok * 2 * 4;   // int [E*Ntok]
constexpr size_t OFF_WHT  = OFF_LIST + (size_t)E_ * Ntok * 4;
constexpr size_t OFF_WIT  = OFF_WHT + (size_t)E_ * G4 * H_ * 2;
constexpr size_t OFF_WOT  = OFF_WIT + (size_t)E_ * G4 * I_ * 2;
constexpr size_t OFF_XP   = OFF_WOT + (size_t)E_ * O_ * H_ * 2;
constexpr size_t WS_NEED  = OFF_XP + (size_t)Ntok * 2 * G4 * 2;

DI float sigf(float v) { return 1.f / (1.f + __expf(-v)); }
DI float tanh_(float v) { float e = __expf(2.f * v); return 1.f - 2.f / (e + 1.f); }

DI bf16x8 pack8(float4 a, float4 b) {
  bf16x8 r;
  r[0] = (bf16_t)a.x; r[1] = (bf16_t)a.y; r[2] = (bf16_t)a.z; r[3] = (bf16_t)a.w;
  r[4] = (bf16_t)b.x; r[5] = (bf16_t)b.y; r[6] = (bf16_t)b.z; r[7] = (bf16_t)b.w;
  return r;
}

// -------- prep: transpose fp32 [512][Cdim] -> bf16 [Cdim][512], col-perm (Wh),
// pre-swizzled (elem k ^= (c&7)<<3) so later LDS staging is a linear copy.
__global__ void k_prep(const float* __restrict__ src, bf16_t* __restrict__ dst,
                       int Cdim, int perm) {
  __shared__ float tile[32][33];
  int ct = blockIdx.x, kt = blockIdx.y, e = blockIdx.z;
  const float* se = src + (size_t)e * 512 * Cdim;
  bf16_t* de = dst + (size_t)e * Cdim * 512;
  int c = threadIdx.x & 31, r0 = threadIdx.x >> 5;
  for (int s = 0; s < 4; s++) {
    int rr = r0 + s * 8;
    tile[rr][c] = se[(size_t)(kt * 32 + rr) * Cdim + ct * 32 + c];
  }
  __syncthreads();
  int kk = threadIdx.x & 31, c0 = threadIdx.x >> 5;
  for (int s = 0; s < 4; s++) {
    int cc = c0 + s * 8;
    int cg = ct * 32 + cc;
    int vc = perm ? (((cg & 511) >> 4) * 64 + (cg >> 9) * 16 + (cg & 15)) : cg;
    int kg = kt * 32 + kk;
    de[(size_t)vc * 512 + (kg ^ ((vc & 7) << 3))] = (bf16_t)tile[kk][cc];
  }
}

// -------- router: fp64 logits, top-2 (tie -> lowest idx), softmax, lists+mask
__global__ void k_router(const float* __restrict__ x, const float* __restrict__ rww,
                         const float* __restrict__ rwb, int* __restrict__ topidx,
                         float* __restrict__ rwgt, int* __restrict__ lists,
                         int* __restrict__ cnt, u64* __restrict__ rowmask) {
  int n = blockIdx.x * 4 + (threadIdx.x >> 6);
  int l = threadIdx.x & 63;
  const float* xr = x + (size_t)n * I_;
  double acc[8] = {0, 0, 0, 0, 0, 0, 0, 0};
  for (int ii = 0; ii < 8; ii++) {
    int i = l * 8 + ii;
    double xv = (double)xr[i];
    const float* wr = rww + i * 8;
#pragma unroll
    for (int e = 0; e < 8; e++) acc[e] += xv * (double)wr[e];
  }
#pragma unroll
  for (int off = 32; off > 0; off >>= 1)
#pragma unroll
    for (int e = 0; e < 8; e++) acc[e] += __shfl_xor(acc[e], off, 64);
  if (l == 0) {
    double lg[8];
    for (int e = 0; e < 8; e++) lg[e] = acc[e] + (double)rwb[e];
    int e0 = 0;
    for (int e = 1; e < 8; e++) if (lg[e] > lg[e0]) e0 = e;
    int e1 = -1;
    for (int e = 0; e < 8; e++) { if (e == e0) continue; if (e1 < 0 || lg[e] > lg[e1]) e1 = e; }
    double ed = exp(lg[e1] - lg[e0]);
    float p0 = (float)(1.0 / (1.0 + ed));
    float p1 = (float)(ed / (1.0 + ed));
    topidx[n * 2] = e0; topidx[n * 2 + 1] = e1;
    rwgt[n * 2] = p0; rwgt[n * 2 + 1] = p1;
    int t = n >> 5, bi = n & 31;
    int p = atomicAdd(&cnt[e0], 1); lists[e0 * Ntok + p] = n * 2;
    p = atomicAdd(&cnt[e1], 1);     lists[e1 * Ntok + p] = n * 2 + 1;
    atomicOr(&rowmask[e0 * 128 + t], 1ull << bi);
    atomicOr(&rowmask[e1 * 128 + t], 1ull << (32 + bi));
  }
}

// -------- shared 64x64 MFMA core: A,B in LDS [64][512] swizzled; 4 waves,
// wave = 16 rows x 64 cols (4 n-tiles), K=512
DI void gemm64(const bf16_t* Als, const bf16_t* Bls, int wv, int l, f32x4* acc) {
  int ar = l & 15, kg = l >> 4;
  int arow = wv * 16 + ar;
  int aswz = (ar & 7) << 3;
#pragma unroll
  for (int ks = 0; ks < 16; ks++) {
    int kb = ks * 32 + kg * 8;
    bf16x8 a = *(const bf16x8*)&Als[arow * 512 + (kb ^ aswz)];
#pragma unroll
    for (int q = 0; q < 4; q++) {
      bf16x8 b = *(const bf16x8*)&Bls[(q * 16 + ar) * 512 + (kb ^ aswz)];
      acc[q] = __builtin_amdgcn_mfma_f32_16x16x32_bf16(a, b, acc[q], 0, 0, 0);
    }
  }
}

// -------- grouped GEMM: xp[entry] = x_row @ Wi[e]  (entry = n*2+k)
__launch_bounds__(256, 1)
__global__ void k_xp(const float* __restrict__ x, const bf16_t* __restrict__ Wit,
                     const int* __restrict__ lists, const int* __restrict__ cnt,
                     bf16_t* __restrict__ xp) {
  __shared__ bf16_t Als[64 * 512];
  __shared__ bf16_t Bls[64 * 512];
  __shared__ int ents[64];
  int e = blockIdx.z, ct = blockIdx.x, rt = blockIdx.y;
  int count = cnt[e];
  int rbase = rt * 64;
  if (rbase >= count) return;
  int tid = threadIdx.x;
  if (tid < 64) ents[tid] = (rbase + tid < count) ? lists[e * Ntok + rbase + tid] : -1;
  __syncthreads();
  int rr = tid >> 2, qq = tid & 3;
  int ent = ents[rr];
  int swzr = (rr & 7) << 3;
  if (ent >= 0) {
    const float* xr = x + (size_t)(ent >> 1) * I_ + qq * 128;
#pragma unroll
    for (int i2 = 0; i2 < 16; i2++) {
      float4 a = *(const float4*)(xr + i2 * 8);
      float4 b = *(const float4*)(xr + i2 * 8 + 4);
      *(bf16x8*)&Als[rr * 512 + ((qq * 128 + i2 * 8) ^ swzr)] = pack8(a, b);
    }
  } else {
    bf16x8 z;
    for (int j = 0; j < 8; j++) z[j] = (bf16_t)0.f;
#pragma unroll
    for (int i2 = 0; i2 < 16; i2++)
      *(bf16x8*)&Als[rr * 512 + ((qq * 128 + i2 * 8) ^ swzr)] = z;
  }
  const bf16_t* bs = Wit + ((size_t)e * G4 + ct * 64) * 512;
#pragma unroll
  for (int i2 = 0; i2 < 16; i2++) {
    int o = (i2 * 256 + tid) * 8;
    *(bf16x8*)&Bls[o] = *(const bf16x8*)&bs[o];
  }
  __syncthreads();
  f32x4 acc[4];
  for (int q = 0; q < 4; q++) { f32x4 z = {0.f, 0.f, 0.f, 0.f}; acc[q] = z; }
  int l = tid & 63, wv = tid >> 6;
  gemm64(Als, Bls, wv, l, acc);
#pragma unroll
  for (int q = 0; q < 4; q++)
#pragma unroll
    for (int r = 0; r < 4; r++) {
      int rr2 = wv * 16 + ((l >> 4) << 2) + r;
      int ent2 = ents[rr2];
      if (ent2 >= 0)
        xp[(size_t)ent2 * G4 + ct * 64 + q * 16 + (l & 15)] = (bf16_t)acc[q][r];
    }
}

// -------- per-expert-group barrier (monotonic counter, relaxed agent atomics)
DI void gbar(u32* bar_e, int idx, bool fence) {
  if (fence) __threadfence();
  __syncthreads();
  if (threadIdx.x == 0) {
    __hip_atomic_fetch_add(bar_e, 1u, __ATOMIC_RELAXED, __HIP_MEMORY_SCOPE_AGENT);
    u32 target = 32u * (u32)(idx + 1);
    while (__hip_atomic_load(bar_e, __ATOMIC_RELAXED, __HIP_MEMORY_SCOPE_AGENT) < target)
      __builtin_amdgcn_s_sleep(2);
  }
  __syncthreads();
  if (fence) __threadfence();
}

// -------- recurrence: 256 WGs; e=bid%8 (XCD-local group), w=bid/8 owns
// gate-quad cols j in [16w,16w+16) for all 64 chains. Wh slice LDS-resident.
__launch_bounds__(256, 1)
__global__ void k_rec(const bf16_t* __restrict__ Wht, const bf16_t* __restrict__ xp,
                      const float* __restrict__ bgate, bf16_t* __restrict__ hall,
                      const u64* __restrict__ rowmask, u32* __restrict__ bar,
                      u32* __restrict__ xcdm, u32* __restrict__ xcdg) {
  __shared__ bf16_t Bls[64 * 512];
  int bid = blockIdx.x;
  int e = bid & 7, w = bid >> 3;
  int tid = threadIdx.x, l = tid & 63, wv = tid >> 6;
  const bf16_t* bs = Wht + ((size_t)e * G4 + w * 64) * 512;
#pragma unroll
  for (int i2 = 0; i2 < 16; i2++) {
    int o = (i2 * 256 + tid) * 8;
    *(bf16x8*)&Bls[o] = *(const bf16x8*)&bs[o];
  }
  int jl = l & 15, j = w * 16 + jl;
  float bq[4];
#pragma unroll
  for (int q = 0; q < 4; q++) bq[q] = bgate[e * G4 + q * 512 + j];
  // XCD placement detection (m09: HW_REG_XCC_ID = id 20, 4 bits)
  int xcd = __builtin_amdgcn_s_getreg(20 | (3 << 11)) & 15;
  if (tid == 0) {
    __hip_atomic_fetch_or(&xcdm[e * 16], 1u << xcd, __ATOMIC_RELAXED, __HIP_MEMORY_SCOPE_AGENT);
    __hip_atomic_fetch_or(xcdg, 1u << xcd, __ATOMIC_RELAXED, __HIP_MEMORY_SCOPE_AGENT);
  }
  u32* mybar = &bar[e * 16];
  gbar(mybar, 0, true);
  u32 me = __hip_atomic_load(&xcdm[e * 16], __ATOMIC_RELAXED, __HIP_MEMORY_SCOPE_AGENT);
  u32 mg = __hip_atomic_load(xcdg, __ATOMIC_RELAXED, __HIP_MEMORY_SCOPE_AGENT);
  // fast iff this expert's 32 WGs share one XCD AND detection looks sane
  bool fast = (__popc(me) == 1) && (__popc(mg) > 1);
  float creg[4] = {0.f, 0.f, 0.f, 0.f};
  int ar = l & 15, kg = l >> 4;
  int arow = wv * 16 + ar;
  int aswz = (ar & 7) << 3;
  for (int t = 0; t < 128; t++) {
    const bf16_t* hc = hall + (size_t)t * SLOT + e * ROWS * 512;
    bf16x8 af[16];
#pragma unroll
    for (int ks = 0; ks < 16; ks++)
      af[ks] = *(const bf16x8*)&hc[arow * 512 + ks * 32 + kg * 8];
    f32x4 acc[4];
    for (int q = 0; q < 4; q++) { f32x4 z = {0.f, 0.f, 0.f, 0.f}; acc[q] = z; }
#pragma unroll
    for (int ks = 0; ks < 16; ks++) {
      int kb = ks * 32 + kg * 8;
#pragma unroll
      for (int q = 0; q < 4; q++) {
        bf16x8 b = *(const bf16x8*)&Bls[(q * 16 + ar) * 512 + (kb ^ aswz)];
        acc[q] = __builtin_amdgcn_mfma_f32_16x16x32_bf16(af[ks], b, acc[q], 0, 0, 0);
      }
    }
    u64 mask = rowmask[e * 128 + t];
    bf16_t* hn = hall + (size_t)(t + 1) * SLOT + e * ROWS * 512;
#pragma unroll
    for (int r = 0; r < 4; r++) {
      int row = wv * 16 + ((l >> 4) << 2) + r;
      float gi = acc[0][r] + bq[0];
      float gf = acc[1][r] + bq[1];
      float gg = acc[2][r] + bq[2];
      float go = acc[3][r] + bq[3];
      if ((mask >> row) & 1ull) {
        int n2 = ((t << 5) + (row & 31)) * 2 + (row >> 5);
        const bf16_t* xr = xp + (size_t)n2 * G4;
        gi += (float)xr[j];        gf += (float)xr[512 + j];
        gg += (float)xr[1024 + j]; go += (float)xr[1536 + j];
      }
      float cn = sigf(gf) * creg[r] + sigf(gi) * tanh_(gg);
      creg[r] = cn;
      float hv = sigf(go) * tanh_(cn);
      hn[row * 512 + j] = (bf16_t)hv;
    }
    if (t < 127) gbar(mybar, t + 1, !fast);
  }
}

// -------- grouped output projection: y[n] += rw * (h_sel @ Wo[e] + bo[e])
__launch_bounds__(256, 1)
__global__ void k_out(const bf16_t* __restrict__ hall, const bf16_t* __restrict__ Wot,
                      const float* __restrict__ bo, const int* __restrict__ lists,
                      const int* __restrict__ cnt, const float* __restrict__ rwgt,
                      float* __restrict__ y) {
  __shared__ bf16_t Als[64 * 512];
  __shared__ bf16_t Bls[64 * 512];
  __shared__ int ents[64];
  __shared__ float rws[64];
  int e = blockIdx.z, ct = blockIdx.x, rt = blockIdx.y;
  int count = cnt[e];
  if (rt * 64 >= count) return;
  int tid = threadIdx.x;
  if (tid < 64) {
    int ent = (rt * 64 + tid < count) ? lists[e * Ntok + rt * 64 + tid] : -1;
    ents[tid] = ent;
    rws[tid] = (ent >= 0) ? rwgt[ent] : 0.f;
  }
  __syncthreads();
  int rr = tid >> 2, qq = tid & 3;
  int ent = ents[rr];
  int swzr = (rr & 7) << 3;
  if (ent >= 0) {
    int n = ent >> 1, kk = ent & 1, t = n >> 5;
    const bf16_t* hr = hall + (size_t)(t + 1) * SLOT +
                       (size_t)(e * ROWS + kk * 32 + (n & 31)) * 512 + qq * 128;
#pragma unroll
    for (int i2 = 0; i2 < 16; i2++) {
      bf16x8 v = *(const bf16x8*)(hr + i2 * 8);
      *(bf16x8*)&Als[rr * 512 + ((qq * 128 + i2 * 8) ^ swzr)] = v;
    }
  } else {
    bf16x8 z;
    for (int jz = 0; jz < 8; jz++) z[jz] = (bf16_t)0.f;
#pragma unroll
    for (int i2 = 0; i2 < 16; i2++)
      *(bf16x8*)&Als[rr * 512 + ((qq * 128 + i2 * 8) ^ swzr)] = z;
  }
  const bf16_t* bsrc = Wot + ((size_t)e * O_ + ct * 64) * 512;
#pragma unroll
  for (int i2 = 0; i2 < 16; i2++) {
    int o = (i2 * 256 + tid) * 8;
    *(bf16x8*)&Bls[o] = *(const bf16x8*)&bsrc[o];
  }
  __syncthreads();
  f32x4 acc[4];
  for (int q = 0; q < 4; q++) { f32x4 z = {0.f, 0.f, 0.f, 0.f}; acc[q] = z; }
  int l = tid & 63, wv = tid >> 6;
  gemm64(Als, Bls, wv, l, acc);
  float boq[4];
#pragma unroll
  for (int q = 0; q < 4; q++) boq[q] = bo[e * O_ + ct * 64 + q * 16 + (l & 15)];
#pragma unroll
  for (int q = 0; q < 4; q++)
#pragma unroll
    for (int r = 0; r < 4; r++) {
      int rr2 = wv * 16 + ((l >> 4) << 2) + r;
      int ent2 = ents[rr2];
      if (ent2 >= 0) {
        float val = (acc[q][r] + boq[q]) * rws[rr2];
        unsafeAtomicAdd(&y[(size_t)(ent2 >> 1) * O_ + ct * 64 + q * 16 + (l & 15)], val);
      }
    }
}

extern "C" void kernel_launch(void* const* d_in, const int* in_sizes, int n_in,
                              void* d_out, int out_size, void* d_ws, size_t ws_size,
                              hipStream_t stream) {
  (void)in_sizes; (void)n_in;
  const float* x   = (const float*)d_in[0];
  const float* rww = (const float*)d_in[1];
  const float* rwb = (const float*)d_in[2];
  const float* Wi  = (const float*)d_in[3];
  const float* Wh  = (const float*)d_in[4];
  const float* bg  = (const float*)d_in[5];
  const float* Wo  = (const float*)d_in[6];
  const float* bo  = (const float*)d_in[7];
  float* y = (float*)d_out;
  char* ws = (char*)d_ws;

  if (ws_size < WS_NEED) {
    // signal: output exactly zeros (distinguishable from poison)
    hipMemsetAsync(d_out, 0, (size_t)out_size * 4, stream);
    return;
  }

  int* cnt     = (int*)(ws + OFF_CNT);
  u32* bar     = (u32*)(ws + OFF_BAR);
  u32* xcdm    = (u32*)(ws + OFF_XCDM);
  u32* xcdg    = (u32*)(ws + OFF_XCDG);
  u64* rowmask = (u64*)(ws + OFF_MASK);
  bf16_t* hall = (bf16_t*)(ws + OFF_HALL);
  int* topidx  = (int*)(ws + OFF_TIDX);
  float* rwgt  = (float*)(ws + OFF_RW);
  int* lists   = (int*)(ws + OFF_LIST);
  bf16_t* Wht  = (bf16_t*)(ws + OFF_WHT);
  bf16_t* Wit  = (bf16_t*)(ws + OFF_WIT);
  bf16_t* Wot  = (bf16_t*)(ws + OFF_WOT);
  bf16_t* xp   = (bf16_t*)(ws + OFF_XP);

  hipMemsetAsync(ws, 0, ZERO_BYTES, stream);
  hipMemsetAsync(d_out, 0, (size_t)out_size * 4, stream);

  k_prep<<<dim3(G4 / 32, 16, 8), 256, 0, stream>>>(Wi, Wit, G4, 0);
  k_prep<<<dim3(G4 / 32, 16, 8), 256, 0, stream>>>(Wh, Wht, G4, 1);
  k_prep<<<dim3(O_ / 32, 16, 8), 256, 0, stream>>>(Wo, Wot, O_, 0);
  k_router<<<Ntok / 4, 256, 0, stream>>>(x, rww, rwb, topidx, rwgt, lists, cnt, rowmask);
  k_xp<<<dim3(32, 64, 8), 256, 0, stream>>>(x, Wit, lists, cnt, xp);
  k_rec<<<256, 256, 0, stream>>>(Wht, xp, bg, hall, rowmask, bar, xcdm, xcdg);
  k_out<<<dim3(8, 64, 8), 256, 0, stream>>>(hall, Wot, bo, lists, cnt, rwgt, y);
}

// Round 4
// 987.214 us; speedup vs baseline: 1.2280x; 1.2280x over previous
//
#include <hip/hip_runtime.h>
#include <hip/hip_bf16.h>
#include <cstdint>
#include <cstddef>

#define DI __device__ __forceinline__

typedef __bf16 bf16_t;
typedef bf16_t bf16x8 __attribute__((ext_vector_type(8)));
typedef float f32x4 __attribute__((ext_vector_type(4)));
typedef unsigned int u32;
typedef unsigned long long u64;

// problem constants
constexpr int S_ = 128, B_ = 32, I_ = 512, H_ = 512, O_ = 512, E_ = 8;
constexpr int Ntok = S_ * B_;        // 4096
constexpr int G4 = 4 * H_;           // 2048
constexpr int ROWS = 64;             // 2(k) x 32(batch) chains per expert
constexpr int SLOT = E_ * ROWS * H_; // elems per h_all step slot (262144)

// workspace layout (bytes)
constexpr size_t OFF_CNT  = 0;                               // int[8]
constexpr size_t OFF_XCDM = 64;                              // u32 @ +e*64
constexpr size_t OFF_XCDG = 704;                             // u32
constexpr size_t OFF_DFL  = 1024;                            // u32[8*32]
constexpr size_t OFF_MASK = 2048;                            // u64 [e*128+t] (8KB)
constexpr size_t OFF_FLG  = 10240;                           // u32[8*64] (2KB)
constexpr size_t OFF_HALL = 16384;                           // bf16, 129 slots
constexpr size_t SLOT_B   = (size_t)SLOT * 2;
constexpr size_t ZERO_BYTES = OFF_HALL + SLOT_B;             // zero slot 0 too
constexpr size_t OFF_TIDX = OFF_HALL + 129ull * SLOT_B;      // int [Ntok*2]
constexpr size_t OFF_RW   = OFF_TIDX + (size_t)Ntok * 2 * 4; // float [Ntok*2]
constexpr size_t OFF_LIST = OFF_RW + (size_t)Ntok * 2 * 4;   // int [E*Ntok]
constexpr size_t OFF_WHT  = OFF_LIST + (size_t)E_ * Ntok * 4;
constexpr size_t OFF_WIT  = OFF_WHT + (size_t)E_ * G4 * H_ * 2;
constexpr size_t OFF_WOT  = OFF_WIT + (size_t)E_ * G4 * I_ * 2;
constexpr size_t OFF_XP   = OFF_WOT + (size_t)E_ * O_ * H_ * 2;
constexpr size_t WS_NEED  = OFF_XP + (size_t)Ntok * 2 * G4 * 2;

DI float sigf(float v) { return 1.f / (1.f + __expf(-v)); }
DI float tanh_(float v) { float e = __expf(2.f * v); return 1.f - 2.f / (e + 1.f); }
DI float bfu(u32 s) { u32 x = (s & 0xffffu) << 16; return __builtin_bit_cast(float, x); }

DI bf16x8 pack8(float4 a, float4 b) {
  bf16x8 r;
  r[0] = (bf16_t)a.x; r[1] = (bf16_t)a.y; r[2] = (bf16_t)a.z; r[3] = (bf16_t)a.w;
  r[4] = (bf16_t)b.x; r[5] = (bf16_t)b.y; r[6] = (bf16_t)b.z; r[7] = (bf16_t)b.w;
  return r;
}

// -------- prep: transpose fp32 [512][Cdim] -> bf16 [Cdim][512], col-perm (Wh),
// pre-swizzled (elem k ^= (c&7)<<3) so later LDS staging is a linear copy.
__global__ void k_prep(const float* __restrict__ src, bf16_t* __restrict__ dst,
                       int Cdim, int perm) {
  __shared__ float tile[32][33];
  int ct = blockIdx.x, kt = blockIdx.y, e = blockIdx.z;
  const float* se = src + (size_t)e * 512 * Cdim;
  bf16_t* de = dst + (size_t)e * Cdim * 512;
  int c = threadIdx.x & 31, r0 = threadIdx.x >> 5;
  for (int s = 0; s < 4; s++) {
    int rr = r0 + s * 8;
    tile[rr][c] = se[(size_t)(kt * 32 + rr) * Cdim + ct * 32 + c];
  }
  __syncthreads();
  int kk = threadIdx.x & 31, c0 = threadIdx.x >> 5;
  for (int s = 0; s < 4; s++) {
    int cc = c0 + s * 8;
    int cg = ct * 32 + cc;
    int vc = perm ? (((cg & 511) >> 4) * 64 + (cg >> 9) * 16 + (cg & 15)) : cg;
    int kg = kt * 32 + kk;
    de[(size_t)vc * 512 + (kg ^ ((vc & 7) << 3))] = (bf16_t)tile[kk][cc];
  }
}

// -------- router: fp64 logits, top-2 (tie -> lowest idx), softmax, lists+mask
__global__ void k_router(const float* __restrict__ x, const float* __restrict__ rww,
                         const float* __restrict__ rwb, int* __restrict__ topidx,
                         float* __restrict__ rwgt, int* __restrict__ lists,
                         int* __restrict__ cnt, u64* __restrict__ rowmask) {
  int n = blockIdx.x * 4 + (threadIdx.x >> 6);
  int l = threadIdx.x & 63;
  const float* xr = x + (size_t)n * I_;
  double acc[8] = {0, 0, 0, 0, 0, 0, 0, 0};
  for (int ii = 0; ii < 8; ii++) {
    int i = l * 8 + ii;
    double xv = (double)xr[i];
    const float* wr = rww + i * 8;
#pragma unroll
    for (int e = 0; e < 8; e++) acc[e] += xv * (double)wr[e];
  }
#pragma unroll
  for (int off = 32; off > 0; off >>= 1)
#pragma unroll
    for (int e = 0; e < 8; e++) acc[e] += __shfl_xor(acc[e], off, 64);
  if (l == 0) {
    double lg[8];
    for (int e = 0; e < 8; e++) lg[e] = acc[e] + (double)rwb[e];
    int e0 = 0;
    for (int e = 1; e < 8; e++) if (lg[e] > lg[e0]) e0 = e;
    int e1 = -1;
    for (int e = 0; e < 8; e++) { if (e == e0) continue; if (e1 < 0 || lg[e] > lg[e1]) e1 = e; }
    double ed = exp(lg[e1] - lg[e0]);
    float p0 = (float)(1.0 / (1.0 + ed));
    float p1 = (float)(ed / (1.0 + ed));
    topidx[n * 2] = e0; topidx[n * 2 + 1] = e1;
    rwgt[n * 2] = p0; rwgt[n * 2 + 1] = p1;
    int t = n >> 5, bi = n & 31;
    int p = atomicAdd(&cnt[e0], 1); lists[e0 * Ntok + p] = n * 2;
    p = atomicAdd(&cnt[e1], 1);     lists[e1 * Ntok + p] = n * 2 + 1;
    atomicOr(&rowmask[e0 * 128 + t], 1ull << bi);
    atomicOr(&rowmask[e1 * 128 + t], 1ull << (32 + bi));
  }
}

// -------- shared 64x64 MFMA core: A,B in LDS [64][512] swizzled; 4 waves,
// wave = 16 rows x 64 cols (4 n-tiles), K=512
DI void gemm64(const bf16_t* Als, const bf16_t* Bls, int wv, int l, f32x4* acc) {
  int ar = l & 15, kg = l >> 4;
  int arow = wv * 16 + ar;
  int aswz = (ar & 7) << 3;
#pragma unroll
  for (int ks = 0; ks < 16; ks++) {
    int kb = ks * 32 + kg * 8;
    bf16x8 a = *(const bf16x8*)&Als[arow * 512 + (kb ^ aswz)];
#pragma unroll
    for (int q = 0; q < 4; q++) {
      bf16x8 b = *(const bf16x8*)&Bls[(q * 16 + ar) * 512 + (kb ^ aswz)];
      acc[q] = __builtin_amdgcn_mfma_f32_16x16x32_bf16(a, b, acc[q], 0, 0, 0);
    }
  }
}

// -------- grouped GEMM: xp2[entry][j][quad] = (x_row @ Wi[e]) quad-interleaved
__launch_bounds__(256, 1)
__global__ void k_xp(const float* __restrict__ x, const bf16_t* __restrict__ Wit,
                     const int* __restrict__ lists, const int* __restrict__ cnt,
                     bf16_t* __restrict__ xp2) {
  __shared__ bf16_t Als[64 * 512];
  __shared__ bf16_t Bls[64 * 512];
  __shared__ int ents[64];
  int e = blockIdx.z, ct = blockIdx.x, rt0 = blockIdx.y;
  int count = cnt[e];
  int tid = threadIdx.x;
  // stage B once (reused across row-tiles)
  const bf16_t* bs = Wit + ((size_t)e * G4 + ct * 64) * 512;
#pragma unroll
  for (int i2 = 0; i2 < 16; i2++) {
    int o = (i2 * 256 + tid) * 8;
    *(bf16x8*)&Bls[o] = *(const bf16x8*)&bs[o];
  }
  int l = tid & 63, wv = tid >> 6;
  int rr = tid >> 2, qq = tid & 3;
  int swzr = (rr & 7) << 3;
  for (int rbase = rt0 * 64; rbase < count; rbase += 16 * 64) {
    __syncthreads();  // prior-iter LDS reads done (and B-stage on first iter)
    if (tid < 64) ents[tid] = (rbase + tid < count) ? lists[e * Ntok + rbase + tid] : -1;
    __syncthreads();
    int ent = ents[rr];
    if (ent >= 0) {
      const float* xr = x + (size_t)(ent >> 1) * I_ + qq * 128;
#pragma unroll
      for (int i2 = 0; i2 < 16; i2++) {
        float4 a = *(const float4*)(xr + i2 * 8);
        float4 b = *(const float4*)(xr + i2 * 8 + 4);
        *(bf16x8*)&Als[rr * 512 + ((qq * 128 + i2 * 8) ^ swzr)] = pack8(a, b);
      }
    } else {
      bf16x8 z;
      for (int jz = 0; jz < 8; jz++) z[jz] = (bf16_t)0.f;
#pragma unroll
      for (int i2 = 0; i2 < 16; i2++)
        *(bf16x8*)&Als[rr * 512 + ((qq * 128 + i2 * 8) ^ swzr)] = z;
    }
    __syncthreads();
    f32x4 acc[4];
    for (int q = 0; q < 4; q++) { f32x4 z = {0.f, 0.f, 0.f, 0.f}; acc[q] = z; }
    gemm64(Als, Bls, wv, l, acc);
#pragma unroll
    for (int q = 0; q < 4; q++)
#pragma unroll
      for (int r = 0; r < 4; r++) {
        int rr2 = wv * 16 + ((l >> 4) << 2) + r;
        int ent2 = ents[rr2];
        if (ent2 >= 0) {
          int g = ct * 64 + q * 16 + (l & 15);
          // quad-interleaved: [entry][j=g&511][quad=g>>9]
          xp2[(size_t)ent2 * G4 + (size_t)(g & 511) * 4 + (g >> 9)] = (bf16_t)acc[q][r];
        }
      }
  }
}

// -------- recurrence: 256 WGs; e=bid%8 (XCD-local group), w=bid/8 owns
// gate-quad cols j in [16w,16w+16) for all 64 chains. Wh slice LDS-resident.
// Flag-epoch barrier (no RMW chain); xp prefetched one step ahead.
__launch_bounds__(256, 1)
__global__ void k_rec(const bf16_t* __restrict__ Wht, const bf16_t* __restrict__ xp2,
                      const float* __restrict__ bgate, bf16_t* __restrict__ hall,
                      const u64* __restrict__ rowmask, u32* __restrict__ flags,
                      u32* __restrict__ dfl, u32* __restrict__ xcdm,
                      u32* __restrict__ xcdg) {
  __shared__ bf16_t Bls[64 * 512];
  int bid = blockIdx.x;
  int e = bid & 7, w = bid >> 3;
  int tid = threadIdx.x, l = tid & 63, wv = tid >> 6;
  const bf16_t* bs = Wht + ((size_t)e * G4 + w * 64) * 512;
#pragma unroll
  for (int i2 = 0; i2 < 16; i2++) {
    int o = (i2 * 256 + tid) * 8;
    *(bf16x8*)&Bls[o] = *(const bf16x8*)&bs[o];
  }
  int jl = l & 15, j = w * 16 + jl;
  float bq[4];
#pragma unroll
  for (int q = 0; q < 4; q++) bq[q] = bgate[e * G4 + q * 512 + j];
  // XCD placement detection (m09: HW_REG_XCC_ID = id 20, 4 bits)
  int xcd = __builtin_amdgcn_s_getreg(20 | (3 << 11)) & 15;
  if (tid == 0) {
    __hip_atomic_fetch_or(&xcdm[e * 16], 1u << xcd, __ATOMIC_RELAXED, __HIP_MEMORY_SCOPE_AGENT);
    __hip_atomic_fetch_or(xcdg, 1u << xcd, __ATOMIC_RELAXED, __HIP_MEMORY_SCOPE_AGENT);
    __hip_atomic_store(&dfl[e * 32 + w], 1u, __ATOMIC_RELEASE, __HIP_MEMORY_SCOPE_AGENT);
  }
  // one-time detect barrier over this expert's 32 WGs
  for (;;) {
    u32 f = __hip_atomic_load(&dfl[e * 32 + (l & 31)], __ATOMIC_RELAXED, __HIP_MEMORY_SCOPE_AGENT);
    if (__all((int)(f >= 1u))) break;
    __builtin_amdgcn_s_sleep(1);
  }
  __builtin_amdgcn_sched_barrier(0);  // rule #18: no code motion across the poll
  u32 me = __hip_atomic_load(&xcdm[e * 16], __ATOMIC_RELAXED, __HIP_MEMORY_SCOPE_AGENT);
  u32 mg = __hip_atomic_load(xcdg, __ATOMIC_RELAXED, __HIP_MEMORY_SCOPE_AGENT);
  // fast iff this expert's 32 WGs share one XCD AND detection looks sane
  bool fast = (__popc(me) == 1) && (__popc(mg) > 1);
  __syncthreads();  // Bls staged for all waves

  float creg[4] = {0.f, 0.f, 0.f, 0.f};
  int ar = l & 15, kg = l >> 4;
  int arow = wv * 16 + ar;
  int aswz = (ar & 7) << 3;
  int r0 = wv * 16 + (kg << 2);  // gate/store rows r0..r0+3
  const ushort* xpu = (const ushort*)xp2;

  uint2 xpc[4], xpn[4];
  {  // prefetch xp for t=0
    u64 mk = rowmask[e * 128];
#pragma unroll
    for (int r = 0; r < 4; r++) {
      int row = r0 + r;
      xpc[r].x = 0; xpc[r].y = 0;
      if ((mk >> row) & 1ull) {
        int n2 = ((row & 31)) * 2 + (row >> 5);
        xpc[r] = *(const uint2*)(xpu + ((size_t)n2 * G4 + j * 4));
      }
    }
  }

  for (int t = 0; t < 128; t++) {
    const bf16_t* hc = hall + (size_t)t * SLOT + e * ROWS * 512;
    bf16x8 af[16];
#pragma unroll
    for (int ks = 0; ks < 16; ks++)
      af[ks] = *(const bf16x8*)&hc[arow * 512 + ks * 32 + kg * 8];
    // prefetch xp for t+1 (independent of h -> hides HBM latency)
#pragma unroll
    for (int r = 0; r < 4; r++) { xpn[r].x = 0; xpn[r].y = 0; }
    if (t < 127) {
      u64 mk = rowmask[e * 128 + t + 1];
#pragma unroll
      for (int r = 0; r < 4; r++) {
        int row = r0 + r;
        if ((mk >> row) & 1ull) {
          int n2 = (((t + 1) << 5) + (row & 31)) * 2 + (row >> 5);
          xpn[r] = *(const uint2*)(xpu + ((size_t)n2 * G4 + j * 4));
        }
      }
    }
    f32x4 acc[4];
    for (int q = 0; q < 4; q++) { f32x4 z = {0.f, 0.f, 0.f, 0.f}; acc[q] = z; }
#pragma unroll
    for (int ks = 0; ks < 16; ks++) {
      int kb = ks * 32 + kg * 8;
#pragma unroll
      for (int q = 0; q < 4; q++) {
        bf16x8 b = *(const bf16x8*)&Bls[(q * 16 + ar) * 512 + (kb ^ aswz)];
        acc[q] = __builtin_amdgcn_mfma_f32_16x16x32_bf16(af[ks], b, acc[q], 0, 0, 0);
      }
    }
    bf16_t* hn = hall + (size_t)(t + 1) * SLOT + e * ROWS * 512;
#pragma unroll
    for (int r = 0; r < 4; r++) {
      int row = r0 + r;
      float gi = acc[0][r] + bq[0] + bfu(xpc[r].x);
      float gf = acc[1][r] + bq[1] + bfu(xpc[r].x >> 16);
      float gg = acc[2][r] + bq[2] + bfu(xpc[r].y);
      float go = acc[3][r] + bq[3] + bfu(xpc[r].y >> 16);
      float cn = sigf(gf) * creg[r] + sigf(gi) * tanh_(gg);
      creg[r] = cn;
      hn[row * 512 + j] = (bf16_t)(sigf(go) * tanh_(cn));
    }
#pragma unroll
    for (int r = 0; r < 4; r++) xpc[r] = xpn[r];
    if (t < 127) {
      __syncthreads();            // all h stores of this WG drained (vmcnt 0)
      if (!fast) __threadfence(); // cross-XCD fallback: push to coherent point
      if (tid == 0)
        __hip_atomic_store(&flags[e * 64 + w], (u32)(t + 1), __ATOMIC_RELAXED,
                           __HIP_MEMORY_SCOPE_AGENT);
      u32 tgt = (u32)(t + 1);
      for (;;) {
        u32 f = __hip_atomic_load(&flags[e * 64 + (l & 31)], __ATOMIC_RELAXED,
                                  __HIP_MEMORY_SCOPE_AGENT);
        if (__all((int)(f >= tgt))) break;
        __builtin_amdgcn_s_sleep(1);
      }
      __builtin_amdgcn_sched_barrier(0);  // keep next-step h loads below the poll
      if (!fast) __threadfence();
    }
  }
}

// -------- grouped output projection: y[n] += rw * (h_sel @ Wo[e] + bo[e])
__launch_bounds__(256, 1)
__global__ void k_out(const bf16_t* __restrict__ hall, const bf16_t* __restrict__ Wot,
                      const float* __restrict__ bo, const int* __restrict__ lists,
                      const int* __restrict__ cnt, const float* __restrict__ rwgt,
                      float* __restrict__ y) {
  __shared__ bf16_t Als[64 * 512];
  __shared__ bf16_t Bls[64 * 512];
  __shared__ int ents[64];
  __shared__ float rws[64];
  int e = blockIdx.z, ct = blockIdx.x, rt0 = blockIdx.y;
  int count = cnt[e];
  int tid = threadIdx.x;
  const bf16_t* bsrc = Wot + ((size_t)e * O_ + ct * 64) * 512;
#pragma unroll
  for (int i2 = 0; i2 < 16; i2++) {
    int o = (i2 * 256 + tid) * 8;
    *(bf16x8*)&Bls[o] = *(const bf16x8*)&bsrc[o];
  }
  int l = tid & 63, wv = tid >> 6;
  int rr = tid >> 2, qq = tid & 3;
  int swzr = (rr & 7) << 3;
  float boq[4];
#pragma unroll
  for (int q = 0; q < 4; q++) boq[q] = bo[e * O_ + ct * 64 + q * 16 + (l & 15)];
  for (int rbase = rt0 * 64; rbase < count; rbase += 16 * 64) {
    __syncthreads();
    if (tid < 64) {
      int ent = (rbase + tid < count) ? lists[e * Ntok + rbase + tid] : -1;
      ents[tid] = ent;
      rws[tid] = (ent >= 0) ? rwgt[ent] : 0.f;
    }
    __syncthreads();
    int ent = ents[rr];
    if (ent >= 0) {
      int n = ent >> 1, kk = ent & 1, t = n >> 5;
      const bf16_t* hr = hall + (size_t)(t + 1) * SLOT +
                         (size_t)(e * ROWS + kk * 32 + (n & 31)) * 512 + qq * 128;
#pragma unroll
      for (int i2 = 0; i2 < 16; i2++) {
        bf16x8 v = *(const bf16x8*)(hr + i2 * 8);
        *(bf16x8*)&Als[rr * 512 + ((qq * 128 + i2 * 8) ^ swzr)] = v;
      }
    } else {
      bf16x8 z;
      for (int jz = 0; jz < 8; jz++) z[jz] = (bf16_t)0.f;
#pragma unroll
      for (int i2 = 0; i2 < 16; i2++)
        *(bf16x8*)&Als[rr * 512 + ((qq * 128 + i2 * 8) ^ swzr)] = z;
    }
    __syncthreads();
    f32x4 acc[4];
    for (int q = 0; q < 4; q++) { f32x4 z = {0.f, 0.f, 0.f, 0.f}; acc[q] = z; }
    gemm64(Als, Bls, wv, l, acc);
#pragma unroll
    for (int q = 0; q < 4; q++)
#pragma unroll
      for (int r = 0; r < 4; r++) {
        int rr2 = wv * 16 + ((l >> 4) << 2) + r;
        int ent2 = ents[rr2];
        if (ent2 >= 0) {
          float val = (acc[q][r] + boq[q]) * rws[rr2];
          unsafeAtomicAdd(&y[(size_t)(ent2 >> 1) * O_ + ct * 64 + q * 16 + (l & 15)], val);
        }
      }
  }
}

extern "C" void kernel_launch(void* const* d_in, const int* in_sizes, int n_in,
                              void* d_out, int out_size, void* d_ws, size_t ws_size,
                              hipStream_t stream) {
  (void)in_sizes; (void)n_in;
  const float* x   = (const float*)d_in[0];
  const float* rww = (const float*)d_in[1];
  const float* rwb = (const float*)d_in[2];
  const float* Wi  = (const float*)d_in[3];
  const float* Wh  = (const float*)d_in[4];
  const float* bg  = (const float*)d_in[5];
  const float* Wo  = (const float*)d_in[6];
  const float* bo  = (const float*)d_in[7];
  float* y = (float*)d_out;
  char* ws = (char*)d_ws;

  if (ws_size < WS_NEED) {
    hipMemsetAsync(d_out, 0, (size_t)out_size * 4, stream);
    return;
  }

  int* cnt     = (int*)(ws + OFF_CNT);
  u32* xcdm    = (u32*)(ws + OFF_XCDM);
  u32* xcdg    = (u32*)(ws + OFF_XCDG);
  u32* dfl     = (u32*)(ws + OFF_DFL);
  u64* rowmask = (u64*)(ws + OFF_MASK);
  u32* flags   = (u32*)(ws + OFF_FLG);
  bf16_t* hall = (bf16_t*)(ws + OFF_HALL);
  int* topidx  = (int*)(ws + OFF_TIDX);
  float* rwgt  = (float*)(ws + OFF_RW);
  int* lists   = (int*)(ws + OFF_LIST);
  bf16_t* Wht  = (bf16_t*)(ws + OFF_WHT);
  bf16_t* Wit  = (bf16_t*)(ws + OFF_WIT);
  bf16_t* Wot  = (bf16_t*)(ws + OFF_WOT);
  bf16_t* xp2  = (bf16_t*)(ws + OFF_XP);

  hipMemsetAsync(ws, 0, ZERO_BYTES, stream);
  hipMemsetAsync(d_out, 0, (size_t)out_size * 4, stream);

  k_prep<<<dim3(G4 / 32, 16, 8), 256, 0, stream>>>(Wi, Wit, G4, 0);
  k_prep<<<dim3(G4 / 32, 16, 8), 256, 0, stream>>>(Wh, Wht, G4, 1);
  k_prep<<<dim3(O_ / 32, 16, 8), 256, 0, stream>>>(Wo, Wot, O_, 0);
  k_router<<<Ntok / 4, 256, 0, stream>>>(x, rww, rwb, topidx, rwgt, lists, cnt, rowmask);
  k_xp<<<dim3(32, 16, 8), 256, 0, stream>>>(x, Wit, lists, cnt, xp2);
  k_rec<<<256, 256, 0, stream>>>(Wht, xp2, bg, hall, rowmask, flags, dfl, xcdm, xcdg);
  k_out<<<dim3(8, 16, 8), 256, 0, stream>>>(hall, Wot, bo, lists, cnt, rwgt, y);
}